// Round 6
// baseline (322.448 us; speedup 1.0000x reference)
//
#include <hip/hip_runtime.h>
#include <hip/hip_bf16.h>

// CoverTreeLoss: aw[j] = W[j] + sum(W[ancestors(j)]); logits = x @ aw^T;
// loss = mean(logsumexp(logits[b]) - logits[b, y[b]]).
// B=4096, H=512, T=10000 (pad to 10112 = 79*128), C=16384.
// R10: epilogue lever on the passing R9 base. R8/R9 proved the K-loop is
// insensitive (conflicts +57% -> 0% time; gllds staging -> 0% time), so the
// cost sits in the store path: 164 MB C-write (75% of traffic) serialized
// behind an LDS transpose with 10 barriers. Replace with DIRECT dword stores
// from acc (4x64B segments per wave-store, coalesced), nontemporal to keep
// the write-only logits stream out of L2, issued BEFORE the partials math so
// the VALU/shfl work runs under the store drain. K-loop/partials unchanged.

typedef __bf16 bf16x8 __attribute__((ext_vector_type(8)));
typedef float f32x4 __attribute__((ext_vector_type(4)));
typedef unsigned short u16x8 __attribute__((ext_vector_type(8)));

#define BATCH 4096
#define HID 512
#define TCLS 10000
#define NPAD 10112   // 79 * 128
#define NBLK 79      // col-blocks = partials per row

__device__ __forceinline__ unsigned short f2bf(float f) {
    unsigned u = __float_as_uint(f);
    unsigned r = (u + 0x7fffu + ((u >> 16) & 1u)) >> 16;  // RNE, finite inputs only
    return (unsigned short)r;
}

// async global -> LDS, 16B per lane. LDS dest must be WAVE-UNIFORM; HW lands
// lane l's 16B at dst + l*16. Global src is per-lane. Direct addrspacecasts.
__device__ __forceinline__ void gllds16(const unsigned short* g, unsigned short* l) {
    __builtin_amdgcn_global_load_lds(
        (const __attribute__((address_space(1))) unsigned int*)g,
        (__attribute__((address_space(3))) unsigned int*)l,
        16, 0, 0);
}

// ---------------- kernel 1: x fp32 -> bf16 ----------------
__global__ __launch_bounds__(256) void cvt_x_kernel(const float* __restrict__ x,
                                                    unsigned short* __restrict__ xb, int n) {
    int i = (blockIdx.x * 256 + threadIdx.x) * 4;
    if (i < n) {
        float4 v = *(const float4*)(x + i);
        ushort4 o;
        o.x = f2bf(v.x); o.y = f2bf(v.y); o.z = f2bf(v.z); o.w = f2bf(v.w);
        *(ushort4*)(xb + i) = o;
    }
}

// ---------------- kernel 1b: CSR bounds from sorted segment_id ----------------
__global__ __launch_bounds__(256) void bounds_kernel(const int* __restrict__ seg, int nnz,
                                                     int* __restrict__ start,
                                                     int* __restrict__ end) {
    int i = blockIdx.x * 256 + threadIdx.x;
    if (i >= nnz) return;
    int s = seg[i];
    if (i == 0 || seg[i - 1] != s) start[s] = i;
    if (i == nnz - 1 || seg[i + 1] != s) end[s] = i + 1;
}

// ---------------- kernel 2: added_weights (bf16, zero-padded rows) ----------------
// 2 classes per 256-thread block; float4 row sum; no searches.
__global__ __launch_bounds__(256) void build_aw_kernel(const float* __restrict__ W,
                                                       const int* __restrict__ anc,
                                                       const int* __restrict__ start,
                                                       const int* __restrict__ end,
                                                       unsigned short* __restrict__ awb) {
    int j = blockIdx.x * 2 + (threadIdx.x >> 7);
    int h = (threadIdx.x & 127) * 4;
    unsigned short* dst = awb + (size_t)j * HID + h;
    if (j >= TCLS) {  // padding rows must be zero (GEMM has no guards)
        *(ushort4*)dst = make_ushort4(0, 0, 0, 0);
        return;
    }
    float4 a = *(const float4*)(W + (size_t)j * HID + h);
    int st = start[j], en = end[j];
    for (int k = st; k < en; k++) {
        float4 w = *(const float4*)(W + (size_t)anc[k] * HID + h);
        a.x += w.x; a.y += w.y; a.z += w.z; a.w += w.w;
    }
    ushort4 o;
    o.x = f2bf(a.x); o.y = f2bf(a.y); o.z = f2bf(a.z); o.w = f2bf(a.w);
    *(ushort4*)dst = o;
}

// ---------------- kernel 3: GEMM + fused softmax partials ----------------
#define BM 128
#define BN 128
#define BK 32
__global__ __launch_bounds__(256) void gemm_fused_kernel(const unsigned short* __restrict__ A,
                                                         const unsigned short* __restrict__ B,
                                                         float* __restrict__ C,
                                                         float2* __restrict__ partials) {
    // A tile 8KB + B tile 8KB; pm partials scratch overlays lds_a post-loop.
    __shared__ __align__(16) unsigned char smem[16384];
    unsigned short* lds_a = (unsigned short*)smem;
    unsigned short* lds_b = ((unsigned short*)smem) + BM * BK;
    float2* pm = (float2*)smem;

    // XCD swizzle: 2528 blocks; xcd = cid&7, per XCD rows {xcd, xcd+8, xcd+16,
    // xcd+24} x 79 cols, row-fastest. 4 A-tiles (512KB) stay hot in 4MB L2.
    const int cid = blockIdx.x;
    const int xcd = cid & 7;
    const int lid = cid >> 3;
    const int bm = (xcd + 8 * (lid & 3)) * BM;
    const int cb = lid >> 2;
    const int bn = cb * BN;

    const int tid = threadIdx.x;
    const int wave = tid >> 6;
    const int lane = tid & 63;
    const int l15 = lane & 15;
    const int quad = lane >> 4;
    const int wm = (wave >> 1) * 64;
    const int wn = (wave & 1) * 64;

    f32x4 acc[4][4];
#pragma unroll
    for (int i = 0; i < 4; i++)
#pragma unroll
        for (int j = 0; j < 4; j++) acc[i][j] = (f32x4)0.f;

    // gllds staging: 16 segments of 1KB (16 rows each); wave w owns segments
    // {2w, 2w+1} of A and of B. Lane l sources row 16*seg + (l>>2), 16B slot
    // (l&3); HW writes dst + l*16 -> [128][32] row-major layout.
    const int segA0 = 2 * wave, segA1 = 2 * wave + 1;
    unsigned short* adst0 = lds_a + segA0 * 512;   // wave-uniform dests
    unsigned short* adst1 = lds_a + segA1 * 512;
    unsigned short* bdst0 = lds_b + segA0 * 512;
    unsigned short* bdst1 = lds_b + segA1 * 512;
    const unsigned short* asrc0 = A + (size_t)(bm + 16 * segA0 + (lane >> 2)) * HID + (lane & 3) * 8;
    const unsigned short* asrc1 = A + (size_t)(bm + 16 * segA1 + (lane >> 2)) * HID + (lane & 3) * 8;
    const unsigned short* bsrc0 = B + (size_t)(bn + 16 * segA0 + (lane >> 2)) * HID + (lane & 3) * 8;
    const unsigned short* bsrc1 = B + (size_t)(bn + 16 * segA1 + (lane >> 2)) * HID + (lane & 3) * 8;

    for (int k0 = 0; k0 < HID; k0 += BK) {
        gllds16(asrc0 + k0, adst0);
        gllds16(asrc1 + k0, adst1);
        gllds16(bsrc0 + k0, bdst0);
        gllds16(bsrc1 + k0, bdst1);
        __syncthreads();  // compiler drains vmcnt(0) before s_barrier -> tile ready

        bf16x8 af[4], bfr[4];
#pragma unroll
        for (int mt = 0; mt < 4; mt++)
            af[mt] = *(const bf16x8*)&lds_a[(wm + mt * 16 + l15) * BK + quad * 8];
#pragma unroll
        for (int nt = 0; nt < 4; nt++)
            bfr[nt] = *(const bf16x8*)&lds_b[(wn + nt * 16 + l15) * BK + quad * 8];
#pragma unroll
        for (int mt = 0; mt < 4; mt++)
#pragma unroll
            for (int nt = 0; nt < 4; nt++)
                acc[mt][nt] = __builtin_amdgcn_mfma_f32_16x16x32_bf16(af[mt], bfr[nt],
                                                                      acc[mt][nt], 0, 0, 0);
        __syncthreads();  // all reads done before next iter's gllds overwrite
    }

    // ---- direct C stores from acc: no LDS transpose, no barriers. Issued
    // first so the partials math below runs under the store drain. Per
    // (mt,nt,r) a wave writes 4 x 64B segments (quad = row, l15 = col).
    const int row0 = bm + wm + quad * 4;
    const int col0 = bn + wn + l15;
#pragma unroll
    for (int mt = 0; mt < 4; mt++) {
#pragma unroll
        for (int r = 0; r < 4; r++) {
            float* rowp = C + (size_t)(row0 + mt * 16 + r) * TCLS;
#pragma unroll
            for (int nt = 0; nt < 4; nt++) {
                int col = col0 + nt * 16;
                if (col < TCLS)
                    __builtin_nontemporal_store(acc[mt][nt][r], rowp + col);
            }
        }
    }

    // ---- fused softmax partials (per 128-col block, per row) ----
    // pm overlays lds_a; safe: post-loop barrier completed, writes below are
    // barrier-separated from the reads in the tid<128 merge.
#pragma unroll
    for (int mt = 0; mt < 4; mt++) {
#pragma unroll
        for (int r = 0; r < 4; r++) {
            float v[4];
#pragma unroll
            for (int nt = 0; nt < 4; nt++)
                v[nt] = (col0 + nt * 16 < TCLS) ? acc[mt][nt][r] : -1e30f;
            float m = fmaxf(fmaxf(v[0], v[1]), fmaxf(v[2], v[3]));
#pragma unroll
            for (int off = 1; off < 16; off <<= 1)
                m = fmaxf(m, __shfl_xor(m, off, 64));
            float s = __expf(v[0] - m) + __expf(v[1] - m) +
                      __expf(v[2] - m) + __expf(v[3] - m);
#pragma unroll
            for (int off = 1; off < 16; off <<= 1)
                s += __shfl_xor(s, off, 64);
            if (l15 == 0) {
                int rowl = wm + mt * 16 + quad * 4 + r;
                pm[rowl * 2 + (wave & 1)] = make_float2(m, s);
            }
        }
    }
    __syncthreads();
    if (tid < 128) {
        float2 p0 = pm[tid * 2 + 0];
        float2 p1 = pm[tid * 2 + 1];
        float nm = fmaxf(p0.x, p1.x);
        float s = p0.y * __expf(p0.x - nm) + p1.y * __expf(p1.x - nm);
        partials[(size_t)(bm + tid) * NBLK + cb] = make_float2(nm, s);
    }
}

// ---------------- kernel 4: lse from partials + gather -> loss terms ----------------
__global__ __launch_bounds__(256) void lse_kernel(const float2* __restrict__ partials,
                                                  const float* __restrict__ logits,
                                                  const int* __restrict__ y,
                                                  float* __restrict__ terms) {
    int row = blockIdx.x * 4 + (threadIdx.x >> 6);
    int lane = threadIdx.x & 63;
    float m = -1e30f, s = 0.f;
    if (lane < NBLK) {
        float2 p = partials[(size_t)row * NBLK + lane];
        m = p.x; s = p.y;
    }
    if (lane + 64 < NBLK) {
        float2 p = partials[(size_t)row * NBLK + lane + 64];
        float nm = fmaxf(m, p.x);
        s = s * __expf(m - nm) + p.y * __expf(p.x - nm);
        m = nm;
    }
#pragma unroll
    for (int off = 1; off < 64; off <<= 1) {
        float om = __shfl_xor(m, off, 64);
        float os = __shfl_xor(s, off, 64);
        float nm = fmaxf(m, om);
        s = s * __expf(m - nm) + os * __expf(om - nm);
        m = nm;
    }
    if (lane == 0)
        terms[row] = m + __logf(s) - logits[(size_t)row * TCLS + y[row]];
}

// ---------------- kernel 5: mean of terms -> d_out[0] ----------------
__global__ __launch_bounds__(256) void reduce_loss_kernel(const float* __restrict__ terms,
                                                          float* __restrict__ out) {
    float s = 0.f;
    for (int i = threadIdx.x; i < BATCH; i += 256) s += terms[i];
#pragma unroll
    for (int off = 32; off > 0; off >>= 1) s += __shfl_down(s, off, 64);
    __shared__ float sh[4];
    if ((threadIdx.x & 63) == 0) sh[threadIdx.x >> 6] = s;
    __syncthreads();
    if (threadIdx.x == 0) out[0] = (sh[0] + sh[1] + sh[2] + sh[3]) * (1.0f / BATCH);
}

extern "C" void kernel_launch(void* const* d_in, const int* in_sizes, int n_in,
                              void* d_out, int out_size, void* d_ws, size_t ws_size,
                              hipStream_t stream) {
    const float* x = (const float*)d_in[0];
    const int* y = (const int*)d_in[1];
    const float* W = (const float*)d_in[2];
    const int* anc = (const int*)d_in[3];
    const int* seg = (const int*)d_in[4];
    int nnz = in_sizes[3];

    unsigned short* xb = (unsigned short*)d_ws;                 // 4 MB
    unsigned short* awb = xb + (size_t)BATCH * HID;             // 10.35 MB
    float2* partials = (float2*)(awb + (size_t)NPAD * HID);     // 2.59 MB
    float* terms = (float*)(partials + (size_t)BATCH * NBLK);   // 16 KB
    int* start = (int*)(terms + BATCH);                         // 40 KB
    int* end = start + TCLS;                                    // 40 KB
    float* loss = (float*)d_out;
    float* logits = loss + 1;                                   // [BATCH, TCLS]

    cvt_x_kernel<<<(BATCH * HID) / (256 * 4), 256, 0, stream>>>(x, xb, BATCH * HID);
    bounds_kernel<<<(nnz + 255) / 256, 256, 0, stream>>>(seg, nnz, start, end);
    build_aw_kernel<<<NPAD / 2, 256, 0, stream>>>(W, anc, start, end, awb);
    gemm_fused_kernel<<<(NPAD / BN) * (BATCH / BM), 256, 0, stream>>>(xb, awb, logits, partials);
    lse_kernel<<<BATCH / 4, 256, 0, stream>>>(partials, logits, y, terms);
    reduce_loss_kernel<<<1, 256, 0, stream>>>(terms, loss);
}

// Round 7
// 299.093 us; speedup vs baseline: 1.0781x; 1.0781x over previous
//
#include <hip/hip_runtime.h>
#include <hip/hip_bf16.h>

// CoverTreeLoss: aw[j] = W[j] + sum(W[ancestors(j)]); logits = x @ aw^T;
// loss = mean(logsumexp(logits[b]) - logits[b, y[b]]).
// B=4096, H=512, T=10000 (pad to 10112 = 79*128), C=16384.
// R11: discriminating experiment on the gemm K-loop. R8/R9/R10 proved
// conflicts/staging/epilogue are all non-bottlenecks (zero time delta).
// Remaining suspect: per-iteration exposed latency at the barrier+vmcnt(0)
// drain, paid 16x in lockstep. This round: BK 32 -> 64 (8 iters), same total
// MFMA/ds_read/gllds work, HALF the drain events. Single 32KB LDS buffer,
// same two-barrier template (parameter change, not a new sync structure).
// Stores: plain dword (R10's nontemporal bypassed L2 write-combine, +53MB).

typedef __bf16 bf16x8 __attribute__((ext_vector_type(8)));
typedef float f32x4 __attribute__((ext_vector_type(4)));

#define BATCH 4096
#define HID 512
#define TCLS 10000
#define NPAD 10112   // 79 * 128
#define NBLK 79      // col-blocks = partials per row

__device__ __forceinline__ unsigned short f2bf(float f) {
    unsigned u = __float_as_uint(f);
    unsigned r = (u + 0x7fffu + ((u >> 16) & 1u)) >> 16;  // RNE, finite inputs only
    return (unsigned short)r;
}

// async global -> LDS, 16B per lane. LDS dest must be WAVE-UNIFORM; HW lands
// lane l's 16B at dst + l*16. Global src is per-lane. Direct addrspacecasts.
__device__ __forceinline__ void gllds16(const unsigned short* g, unsigned short* l) {
    __builtin_amdgcn_global_load_lds(
        (const __attribute__((address_space(1))) unsigned int*)g,
        (__attribute__((address_space(3))) unsigned int*)l,
        16, 0, 0);
}

// ---------------- kernel 1: x fp32 -> bf16 ----------------
__global__ __launch_bounds__(256) void cvt_x_kernel(const float* __restrict__ x,
                                                    unsigned short* __restrict__ xb, int n) {
    int i = (blockIdx.x * 256 + threadIdx.x) * 4;
    if (i < n) {
        float4 v = *(const float4*)(x + i);
        ushort4 o;
        o.x = f2bf(v.x); o.y = f2bf(v.y); o.z = f2bf(v.z); o.w = f2bf(v.w);
        *(ushort4*)(xb + i) = o;
    }
}

// ---------------- kernel 1b: CSR bounds from sorted segment_id ----------------
__global__ __launch_bounds__(256) void bounds_kernel(const int* __restrict__ seg, int nnz,
                                                     int* __restrict__ start,
                                                     int* __restrict__ end) {
    int i = blockIdx.x * 256 + threadIdx.x;
    if (i >= nnz) return;
    int s = seg[i];
    if (i == 0 || seg[i - 1] != s) start[s] = i;
    if (i == nnz - 1 || seg[i + 1] != s) end[s] = i + 1;
}

// ---------------- kernel 2: added_weights (bf16, zero-padded rows) ----------------
// 2 classes per 256-thread block; float4 row sum; no searches.
__global__ __launch_bounds__(256) void build_aw_kernel(const float* __restrict__ W,
                                                       const int* __restrict__ anc,
                                                       const int* __restrict__ start,
                                                       const int* __restrict__ end,
                                                       unsigned short* __restrict__ awb) {
    int j = blockIdx.x * 2 + (threadIdx.x >> 7);
    int h = (threadIdx.x & 127) * 4;
    unsigned short* dst = awb + (size_t)j * HID + h;
    if (j >= TCLS) {  // padding rows must be zero (GEMM has no guards)
        *(ushort4*)dst = make_ushort4(0, 0, 0, 0);
        return;
    }
    float4 a = *(const float4*)(W + (size_t)j * HID + h);
    int st = start[j], en = end[j];
    for (int k = st; k < en; k++) {
        float4 w = *(const float4*)(W + (size_t)anc[k] * HID + h);
        a.x += w.x; a.y += w.y; a.z += w.z; a.w += w.w;
    }
    ushort4 o;
    o.x = f2bf(a.x); o.y = f2bf(a.y); o.z = f2bf(a.z); o.w = f2bf(a.w);
    *(ushort4*)dst = o;
}

// ---------------- kernel 3: GEMM + fused softmax partials ----------------
#define BM 128
#define BN 128
#define BK 64
#define KSTEPS 8   // HID / BK
__global__ __launch_bounds__(256) void gemm_fused_kernel(const unsigned short* __restrict__ A,
                                                         const unsigned short* __restrict__ B,
                                                         float* __restrict__ C,
                                                         float2* __restrict__ partials) {
    // A tile [128][64] shorts (16KB) + B tile same = 32KB single buffer.
    __shared__ __align__(16) unsigned char smem[32768];
    unsigned short* lds_a = (unsigned short*)smem;
    unsigned short* lds_b = ((unsigned short*)smem) + BM * BK;
    float2* pm = (float2*)smem;

    // XCD swizzle: 2528 blocks; xcd = cid&7, per XCD rows {xcd, xcd+8, xcd+16,
    // xcd+24} x 79 cols, row-fastest. 4 A-tiles (512KB) stay hot in 4MB L2.
    const int cid = blockIdx.x;
    const int xcd = cid & 7;
    const int lid = cid >> 3;
    const int bm = (xcd + 8 * (lid & 3)) * BM;
    const int cb = lid >> 2;
    const int bn = cb * BN;

    const int tid = threadIdx.x;
    const int wave = tid >> 6;
    const int lane = tid & 63;
    const int l15 = lane & 15;
    const int quad = lane >> 4;
    const int wm = (wave >> 1) * 64;
    const int wn = (wave & 1) * 64;

    f32x4 acc[4][4];
#pragma unroll
    for (int i = 0; i < 4; i++)
#pragma unroll
        for (int j = 0; j < 4; j++) acc[i][j] = (f32x4)0.f;

    // gllds staging, [128][64] row-major: wave w owns rows 32w..32w+31 of A
    // and B; 4 chunks q of 1KB each (8 rows). Lane l of chunk q sources row
    // 32w + 8q + (l>>3), 16B group (l&7); HW lands it at dst + l*16.
    unsigned short* a_dst[4];
    unsigned short* b_dst[4];
    const unsigned short* a_src[4];
    const unsigned short* b_src[4];
#pragma unroll
    for (int q = 0; q < 4; q++) {
        a_dst[q] = lds_a + wave * 2048 + q * 512;   // wave-uniform
        b_dst[q] = lds_b + wave * 2048 + q * 512;
        int row = 32 * wave + 8 * q + (lane >> 3);
        int col = (lane & 7) * 8;
        a_src[q] = A + (size_t)(bm + row) * HID + col;
        b_src[q] = B + (size_t)(bn + row) * HID + col;
    }

    for (int k0 = 0; k0 < HID; k0 += BK) {
#pragma unroll
        for (int q = 0; q < 4; q++) gllds16(a_src[q] + k0, a_dst[q]);
#pragma unroll
        for (int q = 0; q < 4; q++) gllds16(b_src[q] + k0, b_dst[q]);
        __syncthreads();  // drains vmcnt(0) -> tile ready

#pragma unroll
        for (int kk = 0; kk < BK; kk += 32) {
            bf16x8 af[4], bfr[4];
#pragma unroll
            for (int mt = 0; mt < 4; mt++)
                af[mt] = *(const bf16x8*)&lds_a[(wm + mt * 16 + l15) * BK + kk + quad * 8];
#pragma unroll
            for (int nt = 0; nt < 4; nt++)
                bfr[nt] = *(const bf16x8*)&lds_b[(wn + nt * 16 + l15) * BK + kk + quad * 8];
#pragma unroll
            for (int mt = 0; mt < 4; mt++)
#pragma unroll
                for (int nt = 0; nt < 4; nt++)
                    acc[mt][nt] = __builtin_amdgcn_mfma_f32_16x16x32_bf16(af[mt], bfr[nt],
                                                                          acc[mt][nt], 0, 0, 0);
        }
        __syncthreads();  // all reads done before next iter's gllds overwrite
    }

    // ---- direct C stores from acc (plain dword; L2 write-back merges lines).
    // Issued first so the partials math runs under the store drain.
    const int row0 = bm + wm + quad * 4;
    const int col0 = bn + wn + l15;
#pragma unroll
    for (int mt = 0; mt < 4; mt++) {
#pragma unroll
        for (int r = 0; r < 4; r++) {
            float* rowp = C + (size_t)(row0 + mt * 16 + r) * TCLS;
#pragma unroll
            for (int nt = 0; nt < 4; nt++) {
                int col = col0 + nt * 16;
                if (col < TCLS) rowp[col] = acc[mt][nt][r];
            }
        }
    }

    // ---- fused softmax partials (per 128-col block, per row) ----
    // pm overlays lds_a; safe: post-loop barrier done, then barrier before read.
#pragma unroll
    for (int mt = 0; mt < 4; mt++) {
#pragma unroll
        for (int r = 0; r < 4; r++) {
            float v[4];
#pragma unroll
            for (int nt = 0; nt < 4; nt++)
                v[nt] = (col0 + nt * 16 < TCLS) ? acc[mt][nt][r] : -1e30f;
            float m = fmaxf(fmaxf(v[0], v[1]), fmaxf(v[2], v[3]));
#pragma unroll
            for (int off = 1; off < 16; off <<= 1)
                m = fmaxf(m, __shfl_xor(m, off, 64));
            float s = __expf(v[0] - m) + __expf(v[1] - m) +
                      __expf(v[2] - m) + __expf(v[3] - m);
#pragma unroll
            for (int off = 1; off < 16; off <<= 1)
                s += __shfl_xor(s, off, 64);
            if (l15 == 0) {
                int rowl = wm + mt * 16 + quad * 4 + r;
                pm[rowl * 2 + (wave & 1)] = make_float2(m, s);
            }
        }
    }
    __syncthreads();
    if (tid < 128) {
        float2 p0 = pm[tid * 2 + 0];
        float2 p1 = pm[tid * 2 + 1];
        float nm = fmaxf(p0.x, p1.x);
        float s = p0.y * __expf(p0.x - nm) + p1.y * __expf(p1.x - nm);
        partials[(size_t)(bm + tid) * NBLK + cb] = make_float2(nm, s);
    }
}

// ---------------- kernel 4: lse from partials + gather -> loss terms ----------------
__global__ __launch_bounds__(256) void lse_kernel(const float2* __restrict__ partials,
                                                  const float* __restrict__ logits,
                                                  const int* __restrict__ y,
                                                  float* __restrict__ terms) {
    int row = blockIdx.x * 4 + (threadIdx.x >> 6);
    int lane = threadIdx.x & 63;
    float m = -1e30f, s = 0.f;
    if (lane < NBLK) {
        float2 p = partials[(size_t)row * NBLK + lane];
        m = p.x; s = p.y;
    }
    if (lane + 64 < NBLK) {
        float2 p = partials[(size_t)row * NBLK + lane + 64];
        float nm = fmaxf(m, p.x);
        s = s * __expf(m - nm) + p.y * __expf(p.x - nm);
        m = nm;
    }
#pragma unroll
    for (int off = 1; off < 64; off <<= 1) {
        float om = __shfl_xor(m, off, 64);
        float os = __shfl_xor(s, off, 64);
        float nm = fmaxf(m, om);
        s = s * __expf(m - nm) + os * __expf(om - nm);
        m = nm;
    }
    if (lane == 0)
        terms[row] = m + __logf(s) - logits[(size_t)row * TCLS + y[row]];
}

// ---------------- kernel 5: mean of terms -> d_out[0] ----------------
__global__ __launch_bounds__(256) void reduce_loss_kernel(const float* __restrict__ terms,
                                                          float* __restrict__ out) {
    float s = 0.f;
    for (int i = threadIdx.x; i < BATCH; i += 256) s += terms[i];
#pragma unroll
    for (int off = 32; off > 0; off >>= 1) s += __shfl_down(s, off, 64);
    __shared__ float sh[4];
    if ((threadIdx.x & 63) == 0) sh[threadIdx.x >> 6] = s;
    __syncthreads();
    if (threadIdx.x == 0) out[0] = (sh[0] + sh[1] + sh[2] + sh[3]) * (1.0f / BATCH);
}

extern "C" void kernel_launch(void* const* d_in, const int* in_sizes, int n_in,
                              void* d_out, int out_size, void* d_ws, size_t ws_size,
                              hipStream_t stream) {
    const float* x = (const float*)d_in[0];
    const int* y = (const int*)d_in[1];
    const float* W = (const float*)d_in[2];
    const int* anc = (const int*)d_in[3];
    const int* seg = (const int*)d_in[4];
    int nnz = in_sizes[3];

    unsigned short* xb = (unsigned short*)d_ws;                 // 4 MB
    unsigned short* awb = xb + (size_t)BATCH * HID;             // 10.35 MB
    float2* partials = (float2*)(awb + (size_t)NPAD * HID);     // 2.59 MB
    float* terms = (float*)(partials + (size_t)BATCH * NBLK);   // 16 KB
    int* start = (int*)(terms + BATCH);                         // 40 KB
    int* end = start + TCLS;                                    // 40 KB
    float* loss = (float*)d_out;
    float* logits = loss + 1;                                   // [BATCH, TCLS]

    cvt_x_kernel<<<(BATCH * HID) / (256 * 4), 256, 0, stream>>>(x, xb, BATCH * HID);
    bounds_kernel<<<(nnz + 255) / 256, 256, 0, stream>>>(seg, nnz, start, end);
    build_aw_kernel<<<NPAD / 2, 256, 0, stream>>>(W, anc, start, end, awb);
    gemm_fused_kernel<<<(NPAD / BN) * (BATCH / BM), 256, 0, stream>>>(xb, awb, logits, partials);
    lse_kernel<<<BATCH / 4, 256, 0, stream>>>(partials, logits, y, terms);
    reduce_loss_kernel<<<1, 256, 0, stream>>>(terms, loss);
}